// Round 5
// baseline (105.555 us; speedup 1.0000x reference)
//
#include <hip/hip_runtime.h>
#include <math.h>

typedef unsigned short u16;
typedef short bf16x8 __attribute__((ext_vector_type(8)));
typedef float f32x4 __attribute__((ext_vector_type(4)));

// Workspace byte offsets
#define XT_B   0u          // bf16 [4][64][64][128]  NHWC x
#define WF_B   4194304u    // bf16 [9][8][4][64][8]  main A-frags (t,mt,ks,lane,j)
#define WRF_B  4489216u    // bf16 [36][2][64][8]    offmask A-frags (ks',mt,lane,j)
#define BNS_B  4562944u    // f32 [128] folded BN scale
#define BNB_B  4563456u    // f32 [128] folded BN shift

__device__ __forceinline__ u16 f2bf(float f) {
  union { float f; unsigned int i; } v; v.f = f;
  unsigned int i = v.i;
  return (u16)((i + 0x7fffu + ((i >> 16) & 1u)) >> 16);  // RNE
}
__device__ __forceinline__ float ulo(unsigned int u) {
  union { unsigned int i; float f; } v; v.i = u << 16; return v.f;
}
__device__ __forceinline__ float uhi(unsigned int u) {
  union { unsigned int i; float f; } v; v.i = u & 0xffff0000u; return v.f;
}
__device__ __forceinline__ unsigned int pk(float lo, float hi) {
  return (unsigned int)f2bf(lo) | ((unsigned int)f2bf(hi) << 16);
}

// ---------------------------------------------------------------------------
// prep: x -> bf16 NHWC (float4 reads, LDS transpose), weight frag shuffles,
// BN fold. Grid = 1233 x 256.  (unchanged from round 4)
// ---------------------------------------------------------------------------
__global__ __launch_bounds__(256) void prep_kernel(
    const float* __restrict__ x,   const float* __restrict__ ow,
    const float* __restrict__ mw,  const float* __restrict__ wgt,
    const float* __restrict__ gam, const float* __restrict__ bet,
    const float* __restrict__ mean,const float* __restrict__ var,
    char* __restrict__ wsb) {
  int blk = blockIdx.x, tid = threadIdx.x;
  if (blk < 512) {  // transpose 128c x 32x half-plane -> 32x x 128c bf16
    __shared__ u16 tile[32][136];
    int b = blk >> 7, y = (blk >> 1) & 63, xh = blk & 1;
    const float* src = x + (size_t)b * 524288 + y * 64 + xh * 32;
#pragma unroll
    for (int r = 0; r < 4; ++r) {
      int flat = r * 256 + tid;
      int c = flat >> 3, x4 = (flat & 7) * 4;
      float4 v = *(const float4*)(src + c * 4096 + x4);
      tile[x4 + 0][c] = f2bf(v.x);
      tile[x4 + 1][c] = f2bf(v.y);
      tile[x4 + 2][c] = f2bf(v.z);
      tile[x4 + 3][c] = f2bf(v.w);
    }
    __syncthreads();
    u16* dst = (u16*)(wsb + XT_B) + ((b * 64 + y) * 64 + xh * 32) * 128;
#pragma unroll
    for (int r = 0; r < 2; ++r) {
      int flat = r * 256 + tid;
      int xx = flat >> 4, c8 = (flat & 15) * 8;
      *(uint4*)(dst + xx * 128 + c8) = *(const uint4*)&tile[xx][c8];
    }
  } else if (blk < 1088) {  // main-weight A fragments
    int idx = (blk - 512) * 256 + tid;   // < 147456
    int jj = idx & 7, l = (idx >> 3) & 63, ks = (idx >> 9) & 3,
        mt = (idx >> 11) & 7, t = idx >> 14;
    int o = mt * 16 + (l & 15);
    int c = ks * 32 + (l >> 4) * 8 + jj;
    ((u16*)(wsb + WF_B))[idx] = f2bf(wgt[(o * 128 + c) * 9 + t]);
  } else if (blk < 1232) {  // offmask-weight A fragments (27 rows pad to 32)
    int idx = (blk - 1088) * 256 + tid;  // < 36864
    int jj = idx & 7, l = (idx >> 3) & 63, mt = (idx >> 9) & 1, ks = idx >> 10;
    int oc = mt * 16 + (l & 15);
    int k = ks * 32 + (l >> 4) * 8 + jj;
    int t = k >> 7, c = k & 127;
    float v = 0.f;
    if (oc < 18) v = ow[(oc * 128 + c) * 9 + t];
    else if (oc < 27) v = mw[((oc - 18) * 128 + c) * 9 + t];
    ((u16*)(wsb + WRF_B))[idx] = f2bf(v);
  } else {
    if (tid < 128) {
      float s = gam[tid] * rsqrtf(var[tid] + 1e-5f);
      ((float*)(wsb + BNS_B))[tid] = s;
      ((float*)(wsb + BNB_B))[tid] = bet[tid] - mean[tid] * s;
    }
  }
}

// ---------------------------------------------------------------------------
// main (fused): block = (b, ho, half) -> 32 positions x 128 O. 512 threads.
// P1: offset/mask conv, 8 waves = (kh,nt,mt) task split, LDS reduce.
// P2: sampling with explicit 2-deep gather pipeline (branchless clamps).
// P3: 72 MFMA/wave (1 O-tile x 2 N-tiles), A-frag double-buffered.
// Grid 512 x 512. LDS 78.3 KB -> 2 blocks/CU. A-frag L2 traffic halved vs r4.
// ---------------------------------------------------------------------------
__global__ __launch_bounds__(512, 4) void main_kernel(
    const char* __restrict__ wsb, const float* __restrict__ ob,
    const float* __restrict__ mb, float* __restrict__ out) {
  __shared__ __align__(16) char smem[32 * 1160 * 2];  // 74240 B
  __shared__ float soff[32][32];                      // 4096 B
  u16* vbuf = (u16*)smem;      // [32][1160] sampled values (phase 2/3)
  float* pred = (float*)smem;  // [8][16][16] conv partials (phase 1)

  int blk = blockIdx.x;
  int b = blk >> 7, ho = (blk >> 1) & 63, half = blk & 1;
  int p0 = half * 32;
  int tid = threadIdx.x;
  int w = tid >> 6, l = tid & 63, quad = l >> 4, pn = l & 15;

  const u16* XT = (const u16*)(wsb + XT_B);
  const bf16x8* WFv = (const bf16x8*)(wsb + WF_B);
  const bf16x8* WRFv = (const bf16x8*)(wsb + WRF_B);
  bf16x8 bz = {0, 0, 0, 0, 0, 0, 0, 0};

  // ---- phase 1: offset/mask conv partials; wave = (kh, nt, mt) ----
  {
    int mt = w & 1, nt = (w >> 1) & 1, kh = w >> 2;
    int p = nt * 16 + pn;
    f32x4 acc = {0.f, 0.f, 0.f, 0.f};
#pragma unroll
    for (int t = 0; t < 9; ++t) {
      int y = ho + t / 3 - 1;
      int xx = p0 + p + t % 3 - 1;
      bool valid = ((unsigned)y < 64u) && ((unsigned)xx < 64u);
      const u16* bp = XT + ((b * 64 + y) * 64 + xx) * 128 + quad * 8;
#pragma unroll
      for (int kqi = 0; kqi < 2; ++kqi) {
        int kq = kh * 2 + kqi;
        bf16x8 a = WRFv[((t * 4 + kq) * 2 + mt) * 64 + l];
        bf16x8 bb = valid ? *(const bf16x8*)(bp + kq * 32) : bz;
        acc = __builtin_amdgcn_mfma_f32_16x16x32_bf16(a, bb, acc, 0, 0, 0);
      }
    }
#pragma unroll
    for (int r = 0; r < 4; ++r)
      pred[(((kh * 2 + mt) * 2 + nt) * 16 + quad * 4 + r) * 16 + pn] = acc[r];
  }
  __syncthreads();
  // reduce K-halves, add bias, sigmoid masks -> soff[p][oc]
  for (int i = tid; i < 864; i += 512) {
    int oc = i >> 5, p = i & 31;
    int mt = oc >> 4, row = oc & 15, nt = p >> 4, pn2 = p & 15;
    float v = pred[((mt * 2 + nt) * 16 + row) * 16 + pn2]
            + pred[(((2 + mt) * 2 + nt) * 16 + row) * 16 + pn2]
            + (oc < 18 ? ob[oc] : mb[oc - 18]);
    if (oc >= 18) v = 1.f / (1.f + __expf(-v));
    soff[p][oc] = v;
  }
  __syncthreads();

  // ---- phase 2: sampling, explicit 2-deep gather pipeline ----
  {
    int cl = l & 15, pi = l >> 4;
    int p = w * 4 + pi;
    const u16* xb = XT + (size_t)b * 524288 + cl * 8;
    uint4 q00[2], q01[2], q10[2], q11[2];
    float w00[2], w01[2], w10[2], w11[2];

    auto issue = [&](int t, int st) {
      float oy = soff[p][2 * t], ox = soff[p][2 * t + 1], m = soff[p][18 + t];
      float py = (float)(ho + t / 3 - 1) + oy;
      float px = (float)(p0 + p + t % 3 - 1) + ox;
      float y0f = floorf(py), x0f = floorf(px);
      int y0 = (int)y0f, x0 = (int)x0f;
      float ly = py - y0f, lx = px - x0f;
      float vy0 = (y0 >= 0 && y0 < 64) ? 1.f : 0.f;
      float vy1 = (y0 >= -1 && y0 < 63) ? 1.f : 0.f;
      float vx0 = (x0 >= 0 && x0 < 64) ? 1.f : 0.f;
      float vx1 = (x0 >= -1 && x0 < 63) ? 1.f : 0.f;
      int y0c = min(max(y0, 0), 63), y1c = min(max(y0 + 1, 0), 63);
      int x0c = min(max(x0, 0), 63), x1c = min(max(x0 + 1, 0), 63);
      q00[st] = *(const uint4*)(xb + (y0c * 64 + x0c) * 128);
      q01[st] = *(const uint4*)(xb + (y0c * 64 + x1c) * 128);
      q10[st] = *(const uint4*)(xb + (y1c * 64 + x0c) * 128);
      q11[st] = *(const uint4*)(xb + (y1c * 64 + x1c) * 128);
      w00[st] = (1.f - ly) * (1.f - lx) * m * vy0 * vx0;
      w01[st] = (1.f - ly) * lx * m * vy0 * vx1;
      w10[st] = ly * (1.f - lx) * m * vy1 * vx0;
      w11[st] = ly * lx * m * vy1 * vx1;
    };

    issue(0, 0);
#pragma unroll
    for (int t = 0; t < 9; ++t) {
      int cur = t & 1;
      if (t < 8) issue(t + 1, cur ^ 1);  // overlap next tap's gathers
      float a00 = w00[cur], a01 = w01[cur], a10 = w10[cur], a11 = w11[cur];
      uint4 c00 = q00[cur], c01 = q01[cur], c10 = q10[cur], c11 = q11[cur];
      uint4 o;
      o.x = pk(a00 * ulo(c00.x) + a01 * ulo(c01.x) + a10 * ulo(c10.x) + a11 * ulo(c11.x),
               a00 * uhi(c00.x) + a01 * uhi(c01.x) + a10 * uhi(c10.x) + a11 * uhi(c11.x));
      o.y = pk(a00 * ulo(c00.y) + a01 * ulo(c01.y) + a10 * ulo(c10.y) + a11 * ulo(c11.y),
               a00 * uhi(c00.y) + a01 * uhi(c01.y) + a10 * uhi(c10.y) + a11 * uhi(c11.y));
      o.z = pk(a00 * ulo(c00.z) + a01 * ulo(c01.z) + a10 * ulo(c10.z) + a11 * ulo(c11.z),
               a00 * uhi(c00.z) + a01 * uhi(c01.z) + a10 * uhi(c10.z) + a11 * uhi(c11.z));
      o.w = pk(a00 * ulo(c00.w) + a01 * ulo(c01.w) + a10 * ulo(c10.w) + a11 * ulo(c11.w),
               a00 * uhi(c00.w) + a01 * uhi(c01.w) + a10 * uhi(c10.w) + a11 * uhi(c11.w));
      *(uint4*)&vbuf[p * 1160 + t * 128 + cl * 8] = o;
    }
  }
  __syncthreads();

  // ---- phase 3: GEMM, wave w -> O-tile w, 2 N-tiles, A double-buffered ----
  f32x4 acc0 = {0.f, 0.f, 0.f, 0.f}, acc1 = {0.f, 0.f, 0.f, 0.f};
  bf16x8 A[2][4];
#pragma unroll
  for (int ks = 0; ks < 4; ++ks)
    A[0][ks] = WFv[((0 * 8 + w) * 4 + ks) * 64 + l];
#pragma unroll
  for (int t = 0; t < 9; ++t) {
    int cur = t & 1, nxt = cur ^ 1;
    if (t < 8) {
#pragma unroll
      for (int ks = 0; ks < 4; ++ks)
        A[nxt][ks] = WFv[(((t + 1) * 8 + w) * 4 + ks) * 64 + l];
    }
#pragma unroll
    for (int ks = 0; ks < 4; ++ks) {
      bf16x8 b0 = *(const bf16x8*)&vbuf[pn * 1160 + t * 128 + ks * 32 + quad * 8];
      bf16x8 b1 = *(const bf16x8*)&vbuf[(16 + pn) * 1160 + t * 128 + ks * 32 + quad * 8];
      acc0 = __builtin_amdgcn_mfma_f32_16x16x32_bf16(A[cur][ks], b0, acc0, 0, 0, 0);
      acc1 = __builtin_amdgcn_mfma_f32_16x16x32_bf16(A[cur][ks], b1, acc1, 0, 0, 0);
    }
  }

  // ---- epilogue: BN + SiLU ----
  const float* BNS = (const float*)(wsb + BNS_B);
  const float* BNB = (const float*)(wsb + BNB_B);
#pragma unroll
  for (int nt = 0; nt < 2; ++nt) {
    f32x4 acc = nt ? acc1 : acc0;
#pragma unroll
    for (int r = 0; r < 4; ++r) {
      int o = w * 16 + quad * 4 + r;
      float v = acc[r] * BNS[o] + BNB[o];
      v = v / (1.f + __expf(-v));
      out[((b * 128 + o) * 64 + ho) * 64 + p0 + nt * 16 + pn] = v;
    }
  }
}

extern "C" void kernel_launch(void* const* d_in, const int* in_sizes, int n_in,
                              void* d_out, int out_size, void* d_ws, size_t ws_size,
                              hipStream_t stream) {
  const float* x    = (const float*)d_in[0];
  const float* ow   = (const float*)d_in[1];
  const float* ob   = (const float*)d_in[2];
  const float* mw   = (const float*)d_in[3];
  const float* mb   = (const float*)d_in[4];
  const float* wgt  = (const float*)d_in[5];
  const float* gam  = (const float*)d_in[6];
  const float* bet  = (const float*)d_in[7];
  const float* mean = (const float*)d_in[8];
  const float* var  = (const float*)d_in[9];
  char* wsb = (char*)d_ws;
  float* out = (float*)d_out;

  prep_kernel<<<1233, 256, 0, stream>>>(x, ow, mw, wgt, gam, bet, mean, var, wsb);
  main_kernel<<<512, 512, 0, stream>>>(wsb, ob, mb, out);
}